// Round 1
// baseline (218.693 us; speedup 1.0000x reference)
//
#include <hip/hip_runtime.h>

// GraphFilterRNN: u = lsigf(W_D, S, relu(lsigf(W_A,S,x,bA)+lsigf(W_B,S,h,bB)), bD)
// Horner form: per path, u = ((w3 S + w2) S + w1) S + w0,  w_k = A_k x + B_k h.
// B=16, N=1024, E=1, K=4, feature dims all 128.

typedef __attribute__((ext_vector_type(8))) short short8;
typedef __attribute__((ext_vector_type(4))) float floatx4;

#define AS1 __attribute__((address_space(1)))
#define AS3 __attribute__((address_space(3)))

__device__ __forceinline__ unsigned short f2bf(float f) {
  union { float f; unsigned u; } v; v.f = f;
  unsigned r = v.u + 0x7fffu + ((v.u >> 16) & 1u);
  return (unsigned short)(r >> 16);
}
__device__ __forceinline__ float bf2f(unsigned short b) {
  union { unsigned u; float f; } v; v.u = ((unsigned)b) << 16;
  return v.f;
}
__device__ __forceinline__ unsigned short to_bf(float f) { return f2bf(f); }
__device__ __forceinline__ unsigned short to_bf(unsigned short u) { return u; }

__device__ __forceinline__ void gload16(const void* g, void* l) {
  __builtin_amdgcn_global_load_lds((const AS1 void*)g, (AS3 void*)l, 16, 0, 0);
}

// ---------------------------------------------------------------------------
// GEMM: C[m,n] = sum_k A[m,k] * Bt[n,k]  (+ cinit[m,n]), 128x128 tile, BK=64.
// EPI 0: bf16 out; 1: relu->bf16 out; 2: f32 out; 3: mix (chunk-split dest).
// ---------------------------------------------------------------------------
template<int EPI>
__global__ __launch_bounds__(256)
void gemm_bt(const unsigned short* __restrict__ A, long long aBatch, int lda,
             const unsigned short* __restrict__ Bt, long long bBatch, int ldb,
             int K,
             const unsigned short* __restrict__ cinit, long long ciBatch,
             const float* __restrict__ bias,
             unsigned short* __restrict__ outb, long long obBatch,
             float* __restrict__ outf, long long ofBatch,
             unsigned short* __restrict__ mixv, long long mvBatch)
{
  __shared__ unsigned short As[128 * 64];
  __shared__ unsigned short Bs[128 * 64];

  const int b    = blockIdx.z;
  const int n0   = blockIdx.x * 128;
  const int m0   = blockIdx.y * 128;
  const int tid  = threadIdx.x;
  const int wave = tid >> 6;
  const int lane = tid & 63;
  const int wr   = (wave >> 1) * 64;   // wave row offset in tile
  const int wc   = (wave & 1) * 64;    // wave col offset in tile
  const int l15  = lane & 15;
  const int lhi  = lane >> 4;

  const unsigned short* Ab = A + (long long)b * aBatch;
  const unsigned short* Bb = Bt + (long long)b * bBatch;

  floatx4 acc[4][4];
  if (EPI != 3 && cinit != nullptr) {
    const unsigned short* ci = cinit + (long long)b * ciBatch;
    #pragma unroll
    for (int mi = 0; mi < 4; ++mi)
      #pragma unroll
      for (int ni = 0; ni < 4; ++ni)
        #pragma unroll
        for (int j = 0; j < 4; ++j)
          acc[mi][ni][j] =
            bf2f(ci[(long long)(m0 + wr + mi * 16 + lhi * 4 + j) * 1024 + n0 + wc + ni * 16 + l15]);
  } else {
    #pragma unroll
    for (int mi = 0; mi < 4; ++mi)
      #pragma unroll
      for (int ni = 0; ni < 4; ++ni)
        acc[mi][ni] = (floatx4){0.f, 0.f, 0.f, 0.f};
  }

  for (int k0 = 0; k0 < K; k0 += 64) {
    #pragma unroll
    for (int it = 0; it < 4; ++it) {
      const int q  = (wave * 4 + it) * 64 + lane;
      const int r  = q >> 3;          // row within tile
      const int c8 = (q & 7) * 8;     // k offset (elements)
      gload16(Ab + (long long)(m0 + r) * lda + k0 + c8, As + (wave * 4 + it) * 512);
      gload16(Bb + (long long)(n0 + r) * ldb + k0 + c8, Bs + (wave * 4 + it) * 512);
    }
    __syncthreads();   // drains vmcnt: LDS tiles ready
    #pragma unroll
    for (int kk = 0; kk < 2; ++kk) {
      short8 af[4], bfv[4];
      #pragma unroll
      for (int mi = 0; mi < 4; ++mi)
        af[mi] = *(const short8*)(As + (wr + mi * 16 + l15) * 64 + kk * 32 + lhi * 8);
      #pragma unroll
      for (int ni = 0; ni < 4; ++ni)
        bfv[ni] = *(const short8*)(Bs + (wc + ni * 16 + l15) * 64 + kk * 32 + lhi * 8);
      #pragma unroll
      for (int mi = 0; mi < 4; ++mi)
        #pragma unroll
        for (int ni = 0; ni < 4; ++ni)
          acc[mi][ni] = __builtin_amdgcn_mfma_f32_16x16x32_bf16(af[mi], bfv[ni], acc[mi][ni], 0, 0, 0);
    }
    __syncthreads();   // all waves done with LDS before restage
  }

  if (EPI == 0 || EPI == 1) {
    unsigned short* ob = outb + (long long)b * obBatch;
    #pragma unroll
    for (int mi = 0; mi < 4; ++mi)
      #pragma unroll
      for (int ni = 0; ni < 4; ++ni)
        #pragma unroll
        for (int j = 0; j < 4; ++j) {
          float v = acc[mi][ni][j];
          if (EPI == 1) v = fmaxf(v, 0.f);
          ob[(long long)(m0 + wr + mi * 16 + lhi * 4 + j) * 1024 + n0 + wc + ni * 16 + l15] = f2bf(v);
        }
  } else if (EPI == 2) {
    float* of = outf + (long long)b * ofBatch;
    #pragma unroll
    for (int mi = 0; mi < 4; ++mi)
      #pragma unroll
      for (int ni = 0; ni < 4; ++ni)
        #pragma unroll
        for (int j = 0; j < 4; ++j)
          of[(long long)(m0 + wr + mi * 16 + lhi * 4 + j) * 1024 + n0 + wc + ni * 16 + l15] =
            acc[mi][ni][j];
  } else { // EPI == 3: mix epilogue, rows are chunk kc = blockIdx.y
    const int kc = blockIdx.y;
    unsigned short* dst = (kc == 3) ? (mixv + (long long)b * mvBatch)
                                    : (outb + (long long)b * obBatch + kc * (128 * 1024));
    #pragma unroll
    for (int mi = 0; mi < 4; ++mi)
      #pragma unroll
      for (int ni = 0; ni < 4; ++ni)
        #pragma unroll
        for (int j = 0; j < 4; ++j) {
          const int rl = wr + mi * 16 + lhi * 4 + j;
          float v = acc[mi][ni][j];
          if (kc == 0 && bias != nullptr) v += bias[rl];
          dst[(long long)rl * 1024 + n0 + wc + ni * 16 + l15] = f2bf(v);
        }
  }
}

// ---------------------------------------------------------------------------
// Tiled transpose + convert to bf16: out[c][colOff + r] = bf16(in[r][c])
// ---------------------------------------------------------------------------
template<typename TIN>
__global__ __launch_bounds__(256)
void transpose_bf(const TIN* __restrict__ in, long long inBatch, int C,
                  unsigned short* __restrict__ out, long long outBatch,
                  int outStride, int colOff)
{
  __shared__ TIN t[64][65];
  const int b  = blockIdx.z;
  const int c0 = blockIdx.x * 64;
  const int r0 = blockIdx.y * 64;
  const int tx = threadIdx.x & 63;
  const int ty = threadIdx.x >> 6;   // 0..3
  const TIN* ib = in + (long long)b * inBatch;
  unsigned short* ob = out + (long long)b * outBatch;
  #pragma unroll
  for (int i = 0; i < 64; i += 4)
    t[ty + i][tx] = ib[(long long)(r0 + ty + i) * C + c0 + tx];
  __syncthreads();
  #pragma unroll
  for (int i = 0; i < 64; i += 4)
    ob[(long long)(c0 + ty + i) * outStride + colOff + r0 + tx] = to_bf(t[tx][ty + i]);
}

// ---------------------------------------------------------------------------
// Pack weights into bf16 GEMM-A layout.
// W1[(k*128+h)][g']   g'<128: weight_A[h,0,k,g'], g'>=128: weight_B[h,0,k,g'-128]
// W2[(k*128+f)][h2] = weight_D[f,0,k,h2];  biasAB = bias_A + bias_B
// ---------------------------------------------------------------------------
__global__ __launch_bounds__(256)
void prep_weights(const float* __restrict__ wA, const float* __restrict__ wB,
                  const float* __restrict__ wD,
                  const float* __restrict__ bA, const float* __restrict__ bB,
                  unsigned short* __restrict__ W1, unsigned short* __restrict__ W2,
                  float* __restrict__ biasAB)
{
  const int i = blockIdx.x * 256 + threadIdx.x;
  if (i < 512 * 256) {
    const int row = i >> 8, g2 = i & 255;
    const int k = row >> 7, h = row & 127;
    const float v = (g2 < 128) ? wA[(h * 4 + k) * 128 + g2]
                               : wB[(h * 4 + k) * 128 + (g2 - 128)];
    W1[i] = f2bf(v);
  }
  const int j = i - 512 * 256;
  if (j >= 0 && j < 512 * 128) {
    const int row = j >> 7, h2 = j & 127;
    const int k = row >> 7, f = row & 127;
    W2[j] = f2bf(wD[(f * 4 + k) * 128 + h2]);
  }
  const int l = i - 512 * 256 - 512 * 128;
  if (l >= 0 && l < 128) biasAB[l] = bA[l] + bB[l];
}

// ---------------------------------------------------------------------------
extern "C" void kernel_launch(void* const* d_in, const int* in_sizes, int n_in,
                              void* d_out, int out_size, void* d_ws, size_t ws_size,
                              hipStream_t stream)
{
  const float* x   = (const float*)d_in[0];
  const float* hid = (const float*)d_in[1];
  const float* S   = (const float*)d_in[2];
  const float* wA  = (const float*)d_in[3];
  const float* wB  = (const float*)d_in[4];
  const float* wD  = (const float*)d_in[5];
  const float* bA  = (const float*)d_in[6];
  const float* bB  = (const float*)d_in[7];
  const float* bD  = (const float*)d_in[8];
  float* out = (float*)d_out;

  char* ws = (char*)d_ws;
  auto alloc = [&](size_t bytes) {
    char* p = ws;
    ws += (bytes + 255) & ~(size_t)255;
    return p;
  };
  unsigned short* St   = (unsigned short*)alloc(16ull * 1024 * 1024 * 2); // S^T bf16
  unsigned short* z0t  = (unsigned short*)alloc(16ull * 1024 * 256 * 2);  // [x;h]^T bf16
  unsigned short* cini = (unsigned short*)alloc(16ull * 3 * 128 * 1024 * 2); // w_0..2 / d_0..2
  unsigned short* vb0  = (unsigned short*)alloc(16ull * 128 * 1024 * 2);
  unsigned short* vb1  = (unsigned short*)alloc(16ull * 128 * 1024 * 2);
  unsigned short* hnx  = (unsigned short*)alloc(16ull * 128 * 1024 * 2);  // h_next bf16
  unsigned short* hnt  = (unsigned short*)alloc(16ull * 1024 * 128 * 2);  // h_next^T
  unsigned short* W1   = (unsigned short*)alloc(512 * 256 * 2);
  unsigned short* W2   = (unsigned short*)alloc(512 * 128 * 2);
  float*          bAB  = (float*)alloc(128 * 4);

  const long long NB = 128 * 1024;     // per-batch [128][1024]
  const long long CI = 3 * NB;         // cinit batch stride
  const long long SB = 1024 * 1024;    // S batch stride

  prep_weights<<<dim3(769), 256, 0, stream>>>(wA, wB, wD, bA, bB, W1, W2, bAB);
  transpose_bf<float><<<dim3(16, 16, 16), 256, 0, stream>>>(S, SB, 1024, St, SB, 1024, 0);
  transpose_bf<float><<<dim3(16, 2, 16), 256, 0, stream>>>(x, NB, 1024, z0t, 1024 * 256, 256, 0);
  transpose_bf<float><<<dim3(16, 2, 16), 256, 0, stream>>>(hid, NB, 1024, z0t, 1024 * 256, 256, 128);

  // mix1: w_k = [A_k|B_k] @ [x;h]   (k=3 -> vb0, k<3 -> cini, k=0 += bA+bB)
  gemm_bt<3><<<dim3(8, 4, 16), 256, 0, stream>>>(W1, 0, 256, z0t, 1024 * 256, 256, 256,
      nullptr, 0, bAB, cini, CI, nullptr, 0, vb0, NB);
  // Horner phase 1: v = ((w3 S + w2) S + w1) S + w0 ; h_next = relu(v)
  gemm_bt<0><<<dim3(8, 1, 16), 256, 0, stream>>>(vb0, NB, 1024, St, SB, 1024, 1024,
      cini + 2 * NB, CI, nullptr, vb1, NB, nullptr, 0, nullptr, 0);
  gemm_bt<0><<<dim3(8, 1, 16), 256, 0, stream>>>(vb1, NB, 1024, St, SB, 1024, 1024,
      cini + 1 * NB, CI, nullptr, vb0, NB, nullptr, 0, nullptr, 0);
  gemm_bt<1><<<dim3(8, 1, 16), 256, 0, stream>>>(vb0, NB, 1024, St, SB, 1024, 1024,
      cini, CI, nullptr, hnx, NB, nullptr, 0, nullptr, 0);

  transpose_bf<unsigned short><<<dim3(16, 2, 16), 256, 0, stream>>>(hnx, NB, 1024, hnt, NB, 128, 0);

  // mix2: d_k = D_k @ h_next   (k=3 -> vb0, k<3 -> cini, k=0 += bD)
  gemm_bt<3><<<dim3(8, 4, 16), 256, 0, stream>>>(W2, 0, 128, hnt, NB, 128, 128,
      nullptr, 0, bD, cini, CI, nullptr, 0, vb0, NB);
  // Horner phase 2: out = ((d3 S + d2) S + d1) S + d0
  gemm_bt<0><<<dim3(8, 1, 16), 256, 0, stream>>>(vb0, NB, 1024, St, SB, 1024, 1024,
      cini + 2 * NB, CI, nullptr, vb1, NB, nullptr, 0, nullptr, 0);
  gemm_bt<0><<<dim3(8, 1, 16), 256, 0, stream>>>(vb1, NB, 1024, St, SB, 1024, 1024,
      cini + 1 * NB, CI, nullptr, vb0, NB, nullptr, 0, nullptr, 0);
  gemm_bt<2><<<dim3(8, 1, 16), 256, 0, stream>>>(vb0, NB, 1024, St, SB, 1024, 1024,
      cini, CI, nullptr, nullptr, 0, out, NB, nullptr, 0);
}

// Round 2
// 141.701 us; speedup vs baseline: 1.5433x; 1.5433x over previous
//
#include <hip/hip_runtime.h>

// GraphFilterRNN: u = lsigf(W_D, S, relu(lsigf(W_A,S,x,bA)+lsigf(W_B,S,h,bB)), bD)
// Horner form: per path, u = ((w3 S + w2) S + w1) S + w0,  w_k = A_k x + B_k h.
// B=16, N=1024, E=1, K=4, feature dims all 128.
//
// Round 2: 64x64 tiles (full-GPU grids), 2-phase double-buffered K-loop
// (single barrier per K-step), XOR-swizzled LDS via pre-swizzled global
// source (linear global_load_lds dest + swizzled ds_read).

typedef __attribute__((ext_vector_type(8))) short short8;
typedef __attribute__((ext_vector_type(4))) float floatx4;

#define AS1 __attribute__((address_space(1)))
#define AS3 __attribute__((address_space(3)))

__device__ __forceinline__ unsigned short f2bf(float f) {
  union { float f; unsigned u; } v; v.f = f;
  unsigned r = v.u + 0x7fffu + ((v.u >> 16) & 1u);
  return (unsigned short)(r >> 16);
}
__device__ __forceinline__ float bf2f(unsigned short b) {
  union { unsigned u; float f; } v; v.u = ((unsigned)b) << 16;
  return v.f;
}
__device__ __forceinline__ unsigned short to_bf(float f) { return f2bf(f); }
__device__ __forceinline__ unsigned short to_bf(unsigned short u) { return u; }

__device__ __forceinline__ void gload16(const void* g, void* l) {
  __builtin_amdgcn_global_load_lds((const AS1 void*)g, (AS3 void*)l, 16, 0, 0);
}

// ---------------------------------------------------------------------------
// GEMM: C[m,n] = sum_k A[m,k] * Bt[n,k]  (+ cinit[m,n]), 64x64 tile, BK=64,
// double-buffered LDS, one barrier per K-step.
// EPI 0: bf16 out; 1: relu->bf16 out; 2: f32 out; 3: mix (chunk-split dest).
// LDS layout: logical (row, c16 in 0..7, e in 0..7) stored at short index
//   row*64 + ((c16 ^ (row&7))<<3) + e.  Staging writes linear (q*8) and the
//   global SOURCE address carries the inverse swizzle.
// ---------------------------------------------------------------------------
template<int EPI>
__global__ __launch_bounds__(256)
void gemm_bt(const unsigned short* __restrict__ A, long long aBatch, int lda,
             const unsigned short* __restrict__ Bt, long long bBatch, int ldb,
             int K,
             const unsigned short* __restrict__ cinit, long long ciBatch,
             const float* __restrict__ bias,
             unsigned short* __restrict__ outb, long long obBatch,
             float* __restrict__ outf, long long ofBatch,
             unsigned short* __restrict__ mixv, long long mvBatch)
{
  __shared__ unsigned short As[2][64 * 64];
  __shared__ unsigned short Bs[2][64 * 64];

  const int b    = blockIdx.z;
  const int n0   = blockIdx.x * 64;
  const int m0   = blockIdx.y * 64;
  const int tid  = threadIdx.x;
  const int wave = tid >> 6;
  const int lane = tid & 63;
  const int wr   = (wave >> 1) * 32;   // wave row offset in tile
  const int wc   = (wave & 1) * 32;    // wave col offset in tile
  const int l15  = lane & 15;
  const int lhi  = lane >> 4;

  const unsigned short* Ab = A + (long long)b * aBatch;
  const unsigned short* Bb = Bt + (long long)b * bBatch;

  floatx4 acc[2][2];
  if (EPI != 3 && cinit != nullptr) {
    const unsigned short* ci = cinit + (long long)b * ciBatch;
    #pragma unroll
    for (int mi = 0; mi < 2; ++mi)
      #pragma unroll
      for (int ni = 0; ni < 2; ++ni)
        #pragma unroll
        for (int j = 0; j < 4; ++j)
          acc[mi][ni][j] =
            bf2f(ci[(long long)(m0 + wr + mi * 16 + lhi * 4 + j) * 1024 + n0 + wc + ni * 16 + l15]);
  } else {
    #pragma unroll
    for (int mi = 0; mi < 2; ++mi)
      #pragma unroll
      for (int ni = 0; ni < 2; ++ni)
        acc[mi][ni] = (floatx4){0.f, 0.f, 0.f, 0.f};
  }

  // staging: per wave 2 iterations x 64 lanes x 16B covers one 64x64 bf16 tile
  auto stage = [&](int buf, int k0) {
    #pragma unroll
    for (int it = 0; it < 2; ++it) {
      const int q    = (wave * 2 + it) * 64 + lane;
      const int r    = q >> 3;                       // tile row 0..63
      const int csw  = ((q & 7) ^ (r & 7)) * 8;      // inverse-swizzled k col
      gload16(Ab + (long long)(m0 + r) * lda + k0 + csw, &As[buf][(wave * 2 + it) * 512]);
      gload16(Bb + (long long)(n0 + r) * ldb + k0 + csw, &Bs[buf][(wave * 2 + it) * 512]);
    }
  };

  const int NT = K >> 6;
  stage(0, 0);
  __syncthreads();

  int buf = 0;
  for (int t = 0; t < NT; ++t) {
    if (t + 1 < NT) stage(buf ^ 1, (t + 1) * 64);   // issue next tile first
    #pragma unroll
    for (int kk = 0; kk < 2; ++kk) {
      short8 af[2], bfv[2];
      #pragma unroll
      for (int mi = 0; mi < 2; ++mi) {
        const int row = wr + mi * 16 + l15;
        const int c16 = kk * 4 + lhi;
        af[mi] = *(const short8*)(&As[buf][row * 64 + ((c16 ^ (row & 7)) << 3)]);
      }
      #pragma unroll
      for (int ni = 0; ni < 2; ++ni) {
        const int row = wc + ni * 16 + l15;
        const int c16 = kk * 4 + lhi;
        bfv[ni] = *(const short8*)(&Bs[buf][row * 64 + ((c16 ^ (row & 7)) << 3)]);
      }
      #pragma unroll
      for (int mi = 0; mi < 2; ++mi)
        #pragma unroll
        for (int ni = 0; ni < 2; ++ni)
          acc[mi][ni] = __builtin_amdgcn_mfma_f32_16x16x32_bf16(af[mi], bfv[ni], acc[mi][ni], 0, 0, 0);
    }
    __syncthreads();   // drains vmcnt (next tile staged) + LDS reads done
    buf ^= 1;
  }

  if (EPI == 0 || EPI == 1) {
    unsigned short* ob = outb + (long long)b * obBatch;
    #pragma unroll
    for (int mi = 0; mi < 2; ++mi)
      #pragma unroll
      for (int ni = 0; ni < 2; ++ni)
        #pragma unroll
        for (int j = 0; j < 4; ++j) {
          float v = acc[mi][ni][j];
          if (EPI == 1) v = fmaxf(v, 0.f);
          ob[(long long)(m0 + wr + mi * 16 + lhi * 4 + j) * 1024 + n0 + wc + ni * 16 + l15] = f2bf(v);
        }
  } else if (EPI == 2) {
    float* of = outf + (long long)b * ofBatch;
    #pragma unroll
    for (int mi = 0; mi < 2; ++mi)
      #pragma unroll
      for (int ni = 0; ni < 2; ++ni)
        #pragma unroll
        for (int j = 0; j < 4; ++j)
          of[(long long)(m0 + wr + mi * 16 + lhi * 4 + j) * 1024 + n0 + wc + ni * 16 + l15] =
            acc[mi][ni][j];
  } else { // EPI == 3: mix epilogue; logical M=512 rows, chunk kc = row>>7
    #pragma unroll
    for (int mi = 0; mi < 2; ++mi)
      #pragma unroll
      for (int ni = 0; ni < 2; ++ni)
        #pragma unroll
        for (int j = 0; j < 4; ++j) {
          const int gr = m0 + wr + mi * 16 + lhi * 4 + j;   // 0..511
          const int kc = gr >> 7;
          const int rl = gr & 127;
          unsigned short* dst = (kc == 3) ? (mixv + (long long)b * mvBatch)
                                          : (outb + (long long)b * obBatch + kc * (128 * 1024));
          float v = acc[mi][ni][j];
          if (kc == 0 && bias != nullptr) v += bias[rl];
          dst[(long long)rl * 1024 + n0 + wc + ni * 16 + l15] = f2bf(v);
        }
  }
}

// ---------------------------------------------------------------------------
// Tiled transpose + convert to bf16: out[c][colOff + r] = bf16(in[r][c])
// ---------------------------------------------------------------------------
template<typename TIN>
__global__ __launch_bounds__(256)
void transpose_bf(const TIN* __restrict__ in, long long inBatch, int C,
                  unsigned short* __restrict__ out, long long outBatch,
                  int outStride, int colOff)
{
  __shared__ TIN t[64][65];
  const int b  = blockIdx.z;
  const int c0 = blockIdx.x * 64;
  const int r0 = blockIdx.y * 64;
  const int tx = threadIdx.x & 63;
  const int ty = threadIdx.x >> 6;   // 0..3
  const TIN* ib = in + (long long)b * inBatch;
  unsigned short* ob = out + (long long)b * outBatch;
  #pragma unroll
  for (int i = 0; i < 64; i += 4)
    t[ty + i][tx] = ib[(long long)(r0 + ty + i) * C + c0 + tx];
  __syncthreads();
  #pragma unroll
  for (int i = 0; i < 64; i += 4)
    ob[(long long)(c0 + ty + i) * outStride + colOff + r0 + tx] = to_bf(t[tx][ty + i]);
}

// Combined x / hidden transpose into z0t [node][256] (x -> cols 0..127, h -> 128..255)
__global__ __launch_bounds__(256)
void transpose_xh(const float* __restrict__ x, const float* __restrict__ h,
                  unsigned short* __restrict__ z0t)
{
  __shared__ float t[64][65];
  const int z  = blockIdx.z;            // 0..31
  const int b  = z & 15;
  const float* src = (z < 16) ? (x + (long long)b * (128 * 1024))
                              : (h + (long long)b * (128 * 1024));
  const int colOff = (z < 16) ? 0 : 128;
  const int c0 = blockIdx.x * 64;       // node 0..1023
  const int r0 = blockIdx.y * 64;       // feature 0..127
  const int tx = threadIdx.x & 63;
  const int ty = threadIdx.x >> 6;
  #pragma unroll
  for (int i = 0; i < 64; i += 4)
    t[ty + i][tx] = src[(long long)(r0 + ty + i) * 1024 + c0 + tx];
  __syncthreads();
  unsigned short* ob = z0t + (long long)b * (1024 * 256);
  #pragma unroll
  for (int i = 0; i < 64; i += 4)
    ob[(long long)(c0 + ty + i) * 256 + colOff + r0 + tx] = f2bf(t[tx][ty + i]);
}

// ---------------------------------------------------------------------------
// Pack weights into bf16 GEMM-A layout.
// W1[(k*128+h)][g']   g'<128: weight_A[h,0,k,g'], g'>=128: weight_B[h,0,k,g'-128]
// W2[(k*128+f)][h2] = weight_D[f,0,k,h2];  biasAB = bias_A + bias_B
// ---------------------------------------------------------------------------
__global__ __launch_bounds__(256)
void prep_weights(const float* __restrict__ wA, const float* __restrict__ wB,
                  const float* __restrict__ wD,
                  const float* __restrict__ bA, const float* __restrict__ bB,
                  unsigned short* __restrict__ W1, unsigned short* __restrict__ W2,
                  float* __restrict__ biasAB)
{
  const int i = blockIdx.x * 256 + threadIdx.x;
  if (i < 512 * 256) {
    const int row = i >> 8, g2 = i & 255;
    const int k = row >> 7, h = row & 127;
    const float v = (g2 < 128) ? wA[(h * 4 + k) * 128 + g2]
                               : wB[(h * 4 + k) * 128 + (g2 - 128)];
    W1[i] = f2bf(v);
  }
  const int j = i - 512 * 256;
  if (j >= 0 && j < 512 * 128) {
    const int row = j >> 7, h2 = j & 127;
    const int k = row >> 7, f = row & 127;
    W2[j] = f2bf(wD[(f * 4 + k) * 128 + h2]);
  }
  const int l = i - 512 * 256 - 512 * 128;
  if (l >= 0 && l < 128) biasAB[l] = bA[l] + bB[l];
}

// ---------------------------------------------------------------------------
extern "C" void kernel_launch(void* const* d_in, const int* in_sizes, int n_in,
                              void* d_out, int out_size, void* d_ws, size_t ws_size,
                              hipStream_t stream)
{
  const float* x   = (const float*)d_in[0];
  const float* hid = (const float*)d_in[1];
  const float* S   = (const float*)d_in[2];
  const float* wA  = (const float*)d_in[3];
  const float* wB  = (const float*)d_in[4];
  const float* wD  = (const float*)d_in[5];
  const float* bA  = (const float*)d_in[6];
  const float* bB  = (const float*)d_in[7];
  const float* bD  = (const float*)d_in[8];
  float* out = (float*)d_out;

  char* ws = (char*)d_ws;
  auto alloc = [&](size_t bytes) {
    char* p = ws;
    ws += (bytes + 255) & ~(size_t)255;
    return p;
  };
  unsigned short* St   = (unsigned short*)alloc(16ull * 1024 * 1024 * 2); // S^T bf16
  unsigned short* z0t  = (unsigned short*)alloc(16ull * 1024 * 256 * 2);  // [x;h]^T bf16
  unsigned short* cini = (unsigned short*)alloc(16ull * 3 * 128 * 1024 * 2); // w_0..2 / d_0..2
  unsigned short* vb0  = (unsigned short*)alloc(16ull * 128 * 1024 * 2);
  unsigned short* vb1  = (unsigned short*)alloc(16ull * 128 * 1024 * 2);
  unsigned short* hnx  = (unsigned short*)alloc(16ull * 128 * 1024 * 2);  // h_next bf16
  unsigned short* hnt  = (unsigned short*)alloc(16ull * 1024 * 128 * 2);  // h_next^T
  unsigned short* W1   = (unsigned short*)alloc(512 * 256 * 2);
  unsigned short* W2   = (unsigned short*)alloc(512 * 128 * 2);
  float*          bAB  = (float*)alloc(128 * 4);

  const long long NB = 128 * 1024;     // per-batch [128][1024]
  const long long CI = 3 * NB;         // cinit batch stride
  const long long SB = 1024 * 1024;    // S batch stride

  prep_weights<<<dim3(769), 256, 0, stream>>>(wA, wB, wD, bA, bB, W1, W2, bAB);
  transpose_bf<float><<<dim3(16, 16, 16), 256, 0, stream>>>(S, SB, 1024, St, SB, 1024, 0);
  transpose_xh<<<dim3(16, 2, 32), 256, 0, stream>>>(x, hid, z0t);

  // mix1: w_k = [A_k|B_k] @ [x;h]   (k=3 -> vb0, k<3 -> cini, k=0 += bA+bB)
  gemm_bt<3><<<dim3(16, 8, 16), 256, 0, stream>>>(W1, 0, 256, z0t, 1024 * 256, 256, 256,
      nullptr, 0, bAB, cini, CI, nullptr, 0, vb0, NB);
  // Horner phase 1: v = ((w3 S + w2) S + w1) S + w0 ; h_next = relu(v)
  gemm_bt<0><<<dim3(16, 2, 16), 256, 0, stream>>>(vb0, NB, 1024, St, SB, 1024, 1024,
      cini + 2 * NB, CI, nullptr, vb1, NB, nullptr, 0, nullptr, 0);
  gemm_bt<0><<<dim3(16, 2, 16), 256, 0, stream>>>(vb1, NB, 1024, St, SB, 1024, 1024,
      cini + 1 * NB, CI, nullptr, vb0, NB, nullptr, 0, nullptr, 0);
  gemm_bt<1><<<dim3(16, 2, 16), 256, 0, stream>>>(vb0, NB, 1024, St, SB, 1024, 1024,
      cini, CI, nullptr, hnx, NB, nullptr, 0, nullptr, 0);

  transpose_bf<unsigned short><<<dim3(16, 2, 16), 256, 0, stream>>>(hnx, NB, 1024, hnt, NB, 128, 0);

  // mix2: d_k = D_k @ h_next   (k=3 -> vb0, k<3 -> cini, k=0 += bD)
  gemm_bt<3><<<dim3(16, 8, 16), 256, 0, stream>>>(W2, 0, 128, hnt, NB, 128, 128,
      nullptr, 0, bD, cini, CI, nullptr, 0, vb0, NB);
  // Horner phase 2: out = ((d3 S + d2) S + d1) S + d0
  gemm_bt<0><<<dim3(16, 2, 16), 256, 0, stream>>>(vb0, NB, 1024, St, SB, 1024, 1024,
      cini + 2 * NB, CI, nullptr, vb1, NB, nullptr, 0, nullptr, 0);
  gemm_bt<0><<<dim3(16, 2, 16), 256, 0, stream>>>(vb1, NB, 1024, St, SB, 1024, 1024,
      cini + 1 * NB, CI, nullptr, vb0, NB, nullptr, 0, nullptr, 0);
  gemm_bt<2><<<dim3(16, 2, 16), 256, 0, stream>>>(vb0, NB, 1024, St, SB, 1024, 1024,
      cini, CI, nullptr, nullptr, 0, out, NB, nullptr, 0);
}

// Round 3
// 134.627 us; speedup vs baseline: 1.6244x; 1.0525x over previous
//
#include <hip/hip_runtime.h>

// GraphFilterRNN: u = lsigf(W_D, S, relu(lsigf(W_A,S,x,bA)+lsigf(W_B,S,h,bB)), bD)
// Horner form: per path, u = ((w3 S + w2) S + w1) S + w0,  w_k = A_k x + B_k h.
// B=16, N=1024, E=1, K=4, feature dims all 128.
//
// Round 3: XCD batch-clustered block swizzle. S is per-batch, so each batch's
// S^T panel (2 MB) is private; clustering a batch's blocks onto one XCD makes
// staging L2-resident (4 MiB/XCD) instead of L3-bound. 16 batches / 8 XCDs =
// 2 batches per XCD; swizzle is bijective (total = 8*2*16*MT).

typedef __attribute__((ext_vector_type(8))) short short8;
typedef __attribute__((ext_vector_type(4))) float floatx4;

#define AS1 __attribute__((address_space(1)))
#define AS3 __attribute__((address_space(3)))

__device__ __forceinline__ unsigned short f2bf(float f) {
  union { float f; unsigned u; } v; v.f = f;
  unsigned r = v.u + 0x7fffu + ((v.u >> 16) & 1u);
  return (unsigned short)(r >> 16);
}
__device__ __forceinline__ float bf2f(unsigned short b) {
  union { unsigned u; float f; } v; v.u = ((unsigned)b) << 16;
  return v.f;
}
__device__ __forceinline__ unsigned short to_bf(float f) { return f2bf(f); }
__device__ __forceinline__ unsigned short to_bf(unsigned short u) { return u; }

__device__ __forceinline__ void gload16(const void* g, void* l) {
  __builtin_amdgcn_global_load_lds((const AS1 void*)g, (AS3 void*)l, 16, 0, 0);
}

// ---------------------------------------------------------------------------
// GEMM: C[m,n] = sum_k A[m,k] * Bt[n,k]  (+ cinit[m,n]), 64x64 tile, BK=64,
// double-buffered LDS, one barrier per K-step.
// EPI 0: bf16 out; 1: relu->bf16 out; 2: f32 out; 3: mix (chunk-split dest).
// LDS layout: logical (row, c16 in 0..7, e in 0..7) stored at short index
//   row*64 + ((c16 ^ (row&7))<<3) + e.  Staging writes linear (q*8) and the
//   global SOURCE address carries the inverse swizzle.
// Grid must be (16, MT, 16) with MT = 8 for EPI==3 else 2.
// ---------------------------------------------------------------------------
template<int EPI>
__global__ __launch_bounds__(256)
void gemm_bt(const unsigned short* __restrict__ A, long long aBatch, int lda,
             const unsigned short* __restrict__ Bt, long long bBatch, int ldb,
             int K,
             const unsigned short* __restrict__ cinit, long long ciBatch,
             const float* __restrict__ bias,
             unsigned short* __restrict__ outb, long long obBatch,
             float* __restrict__ outf, long long ofBatch,
             unsigned short* __restrict__ mixv, long long mvBatch)
{
  __shared__ unsigned short As[2][64 * 64];
  __shared__ unsigned short Bs[2][64 * 64];

  // ---- XCD batch-cluster swizzle (bijective) ----
  constexpr int MT   = (EPI == 3) ? 8 : 2;   // m-tiles
  constexpr int PERB = 16 * MT;              // blocks per batch
  const int wgid = blockIdx.x + 16 * (blockIdx.y + MT * blockIdx.z);
  const int xcd  = wgid & 7;                 // hw: wgid round-robins XCDs
  const int idx  = wgid >> 3;                // 0 .. 2*PERB-1
  const int b    = xcd * 2 + idx / PERB;     // batch -> fixed XCD pair
  const int r    = idx % PERB;
  const int n0   = (r & 15) * 64;
  const int m0   = (r >> 4) * 64;

  const int tid  = threadIdx.x;
  const int wave = tid >> 6;
  const int lane = tid & 63;
  const int wr   = (wave >> 1) * 32;   // wave row offset in tile
  const int wc   = (wave & 1) * 32;    // wave col offset in tile
  const int l15  = lane & 15;
  const int lhi  = lane >> 4;

  const unsigned short* Ab = A + (long long)b * aBatch;
  const unsigned short* Bb = Bt + (long long)b * bBatch;

  floatx4 acc[2][2];
  if (EPI != 3 && cinit != nullptr) {
    const unsigned short* ci = cinit + (long long)b * ciBatch;
    #pragma unroll
    for (int mi = 0; mi < 2; ++mi)
      #pragma unroll
      for (int ni = 0; ni < 2; ++ni)
        #pragma unroll
        for (int j = 0; j < 4; ++j)
          acc[mi][ni][j] =
            bf2f(ci[(long long)(m0 + wr + mi * 16 + lhi * 4 + j) * 1024 + n0 + wc + ni * 16 + l15]);
  } else {
    #pragma unroll
    for (int mi = 0; mi < 2; ++mi)
      #pragma unroll
      for (int ni = 0; ni < 2; ++ni)
        acc[mi][ni] = (floatx4){0.f, 0.f, 0.f, 0.f};
  }

  // staging: per wave 2 iterations x 64 lanes x 16B covers one 64x64 bf16 tile
  auto stage = [&](int buf, int k0) {
    #pragma unroll
    for (int it = 0; it < 2; ++it) {
      const int q    = (wave * 2 + it) * 64 + lane;
      const int r2   = q >> 3;                       // tile row 0..63
      const int csw  = ((q & 7) ^ (r2 & 7)) * 8;     // inverse-swizzled k col
      gload16(Ab + (long long)(m0 + r2) * lda + k0 + csw, &As[buf][(wave * 2 + it) * 512]);
      gload16(Bb + (long long)(n0 + r2) * ldb + k0 + csw, &Bs[buf][(wave * 2 + it) * 512]);
    }
  };

  const int NT = K >> 6;
  stage(0, 0);
  __syncthreads();

  int buf = 0;
  for (int t = 0; t < NT; ++t) {
    if (t + 1 < NT) stage(buf ^ 1, (t + 1) * 64);   // issue next tile first
    #pragma unroll
    for (int kk = 0; kk < 2; ++kk) {
      short8 af[2], bfv[2];
      #pragma unroll
      for (int mi = 0; mi < 2; ++mi) {
        const int row = wr + mi * 16 + l15;
        const int c16 = kk * 4 + lhi;
        af[mi] = *(const short8*)(&As[buf][row * 64 + ((c16 ^ (row & 7)) << 3)]);
      }
      #pragma unroll
      for (int ni = 0; ni < 2; ++ni) {
        const int row = wc + ni * 16 + l15;
        const int c16 = kk * 4 + lhi;
        bfv[ni] = *(const short8*)(&Bs[buf][row * 64 + ((c16 ^ (row & 7)) << 3)]);
      }
      #pragma unroll
      for (int mi = 0; mi < 2; ++mi)
        #pragma unroll
        for (int ni = 0; ni < 2; ++ni)
          acc[mi][ni] = __builtin_amdgcn_mfma_f32_16x16x32_bf16(af[mi], bfv[ni], acc[mi][ni], 0, 0, 0);
    }
    __syncthreads();   // drains vmcnt (next tile staged) + LDS reads done
    buf ^= 1;
  }

  if (EPI == 0 || EPI == 1) {
    unsigned short* ob = outb + (long long)b * obBatch;
    #pragma unroll
    for (int mi = 0; mi < 2; ++mi)
      #pragma unroll
      for (int ni = 0; ni < 2; ++ni)
        #pragma unroll
        for (int j = 0; j < 4; ++j) {
          float v = acc[mi][ni][j];
          if (EPI == 1) v = fmaxf(v, 0.f);
          ob[(long long)(m0 + wr + mi * 16 + lhi * 4 + j) * 1024 + n0 + wc + ni * 16 + l15] = f2bf(v);
        }
  } else if (EPI == 2) {
    float* of = outf + (long long)b * ofBatch;
    #pragma unroll
    for (int mi = 0; mi < 2; ++mi)
      #pragma unroll
      for (int ni = 0; ni < 2; ++ni)
        #pragma unroll
        for (int j = 0; j < 4; ++j)
          of[(long long)(m0 + wr + mi * 16 + lhi * 4 + j) * 1024 + n0 + wc + ni * 16 + l15] =
            acc[mi][ni][j];
  } else { // EPI == 3: mix epilogue; logical M=512 rows, chunk kc = row>>7
    #pragma unroll
    for (int mi = 0; mi < 2; ++mi)
      #pragma unroll
      for (int ni = 0; ni < 2; ++ni)
        #pragma unroll
        for (int j = 0; j < 4; ++j) {
          const int gr = m0 + wr + mi * 16 + lhi * 4 + j;   // 0..511
          const int kc = gr >> 7;
          const int rl = gr & 127;
          unsigned short* dst = (kc == 3) ? (mixv + (long long)b * mvBatch)
                                          : (outb + (long long)b * obBatch + kc * (128 * 1024));
          float v = acc[mi][ni][j];
          if (kc == 0 && bias != nullptr) v += bias[rl];
          dst[(long long)rl * 1024 + n0 + wc + ni * 16 + l15] = f2bf(v);
        }
  }
}

// ---------------------------------------------------------------------------
// Tiled transpose + convert to bf16: out[c][colOff + r] = bf16(in[r][c])
// ---------------------------------------------------------------------------
template<typename TIN>
__global__ __launch_bounds__(256)
void transpose_bf(const TIN* __restrict__ in, long long inBatch, int C,
                  unsigned short* __restrict__ out, long long outBatch,
                  int outStride, int colOff)
{
  __shared__ TIN t[64][65];
  const int b  = blockIdx.z;
  const int c0 = blockIdx.x * 64;
  const int r0 = blockIdx.y * 64;
  const int tx = threadIdx.x & 63;
  const int ty = threadIdx.x >> 6;   // 0..3
  const TIN* ib = in + (long long)b * inBatch;
  unsigned short* ob = out + (long long)b * outBatch;
  #pragma unroll
  for (int i = 0; i < 64; i += 4)
    t[ty + i][tx] = ib[(long long)(r0 + ty + i) * C + c0 + tx];
  __syncthreads();
  #pragma unroll
  for (int i = 0; i < 64; i += 4)
    ob[(long long)(c0 + ty + i) * outStride + colOff + r0 + tx] = to_bf(t[tx][ty + i]);
}

// Combined x / hidden transpose into z0t [node][256] (x -> cols 0..127, h -> 128..255)
__global__ __launch_bounds__(256)
void transpose_xh(const float* __restrict__ x, const float* __restrict__ h,
                  unsigned short* __restrict__ z0t)
{
  __shared__ float t[64][65];
  const int z  = blockIdx.z;            // 0..31
  const int b  = z & 15;
  const float* src = (z < 16) ? (x + (long long)b * (128 * 1024))
                              : (h + (long long)b * (128 * 1024));
  const int colOff = (z < 16) ? 0 : 128;
  const int c0 = blockIdx.x * 64;       // node 0..1023
  const int r0 = blockIdx.y * 64;       // feature 0..127
  const int tx = threadIdx.x & 63;
  const int ty = threadIdx.x >> 6;
  #pragma unroll
  for (int i = 0; i < 64; i += 4)
    t[ty + i][tx] = src[(long long)(r0 + ty + i) * 1024 + c0 + tx];
  __syncthreads();
  unsigned short* ob = z0t + (long long)b * (1024 * 256);
  #pragma unroll
  for (int i = 0; i < 64; i += 4)
    ob[(long long)(c0 + ty + i) * 256 + colOff + r0 + tx] = f2bf(t[tx][ty + i]);
}

// ---------------------------------------------------------------------------
// Pack weights into bf16 GEMM-A layout.
// W1[(k*128+h)][g']   g'<128: weight_A[h,0,k,g'], g'>=128: weight_B[h,0,k,g'-128]
// W2[(k*128+f)][h2] = weight_D[f,0,k,h2];  biasAB = bias_A + bias_B
// ---------------------------------------------------------------------------
__global__ __launch_bounds__(256)
void prep_weights(const float* __restrict__ wA, const float* __restrict__ wB,
                  const float* __restrict__ wD,
                  const float* __restrict__ bA, const float* __restrict__ bB,
                  unsigned short* __restrict__ W1, unsigned short* __restrict__ W2,
                  float* __restrict__ biasAB)
{
  const int i = blockIdx.x * 256 + threadIdx.x;
  if (i < 512 * 256) {
    const int row = i >> 8, g2 = i & 255;
    const int k = row >> 7, h = row & 127;
    const float v = (g2 < 128) ? wA[(h * 4 + k) * 128 + g2]
                               : wB[(h * 4 + k) * 128 + (g2 - 128)];
    W1[i] = f2bf(v);
  }
  const int j = i - 512 * 256;
  if (j >= 0 && j < 512 * 128) {
    const int row = j >> 7, h2 = j & 127;
    const int k = row >> 7, f = row & 127;
    W2[j] = f2bf(wD[(f * 4 + k) * 128 + h2]);
  }
  const int l = i - 512 * 256 - 512 * 128;
  if (l >= 0 && l < 128) biasAB[l] = bA[l] + bB[l];
}

// ---------------------------------------------------------------------------
extern "C" void kernel_launch(void* const* d_in, const int* in_sizes, int n_in,
                              void* d_out, int out_size, void* d_ws, size_t ws_size,
                              hipStream_t stream)
{
  const float* x   = (const float*)d_in[0];
  const float* hid = (const float*)d_in[1];
  const float* S   = (const float*)d_in[2];
  const float* wA  = (const float*)d_in[3];
  const float* wB  = (const float*)d_in[4];
  const float* wD  = (const float*)d_in[5];
  const float* bA  = (const float*)d_in[6];
  const float* bB  = (const float*)d_in[7];
  const float* bD  = (const float*)d_in[8];
  float* out = (float*)d_out;

  char* ws = (char*)d_ws;
  auto alloc = [&](size_t bytes) {
    char* p = ws;
    ws += (bytes + 255) & ~(size_t)255;
    return p;
  };
  unsigned short* St   = (unsigned short*)alloc(16ull * 1024 * 1024 * 2); // S^T bf16
  unsigned short* z0t  = (unsigned short*)alloc(16ull * 1024 * 256 * 2);  // [x;h]^T bf16
  unsigned short* cini = (unsigned short*)alloc(16ull * 3 * 128 * 1024 * 2); // w_0..2 / d_0..2
  unsigned short* vb0  = (unsigned short*)alloc(16ull * 128 * 1024 * 2);
  unsigned short* vb1  = (unsigned short*)alloc(16ull * 128 * 1024 * 2);
  unsigned short* hnx  = (unsigned short*)alloc(16ull * 128 * 1024 * 2);  // h_next bf16
  unsigned short* hnt  = (unsigned short*)alloc(16ull * 1024 * 128 * 2);  // h_next^T
  unsigned short* W1   = (unsigned short*)alloc(512 * 256 * 2);
  unsigned short* W2   = (unsigned short*)alloc(512 * 128 * 2);
  float*          bAB  = (float*)alloc(128 * 4);

  const long long NB = 128 * 1024;     // per-batch [128][1024]
  const long long CI = 3 * NB;         // cinit batch stride
  const long long SB = 1024 * 1024;    // S batch stride

  prep_weights<<<dim3(769), 256, 0, stream>>>(wA, wB, wD, bA, bB, W1, W2, bAB);
  transpose_bf<float><<<dim3(16, 16, 16), 256, 0, stream>>>(S, SB, 1024, St, SB, 1024, 0);
  transpose_xh<<<dim3(16, 2, 32), 256, 0, stream>>>(x, hid, z0t);

  // mix1: w_k = [A_k|B_k] @ [x;h]   (k=3 -> vb0, k<3 -> cini, k=0 += bA+bB)
  gemm_bt<3><<<dim3(16, 8, 16), 256, 0, stream>>>(W1, 0, 256, z0t, 1024 * 256, 256, 256,
      nullptr, 0, bAB, cini, CI, nullptr, 0, vb0, NB);
  // Horner phase 1: v = ((w3 S + w2) S + w1) S + w0 ; h_next = relu(v)
  gemm_bt<0><<<dim3(16, 2, 16), 256, 0, stream>>>(vb0, NB, 1024, St, SB, 1024, 1024,
      cini + 2 * NB, CI, nullptr, vb1, NB, nullptr, 0, nullptr, 0);
  gemm_bt<0><<<dim3(16, 2, 16), 256, 0, stream>>>(vb1, NB, 1024, St, SB, 1024, 1024,
      cini + 1 * NB, CI, nullptr, vb0, NB, nullptr, 0, nullptr, 0);
  gemm_bt<1><<<dim3(16, 2, 16), 256, 0, stream>>>(vb0, NB, 1024, St, SB, 1024, 1024,
      cini, CI, nullptr, hnx, NB, nullptr, 0, nullptr, 0);

  transpose_bf<unsigned short><<<dim3(16, 2, 16), 256, 0, stream>>>(hnx, NB, 1024, hnt, NB, 128, 0);

  // mix2: d_k = D_k @ h_next   (k=3 -> vb0, k<3 -> cini, k=0 += bD)
  gemm_bt<3><<<dim3(16, 8, 16), 256, 0, stream>>>(W2, 0, 128, hnt, NB, 128, 128,
      nullptr, 0, bD, cini, CI, nullptr, 0, vb0, NB);
  // Horner phase 2: out = ((d3 S + d2) S + d1) S + d0
  gemm_bt<0><<<dim3(16, 2, 16), 256, 0, stream>>>(vb0, NB, 1024, St, SB, 1024, 1024,
      cini + 2 * NB, CI, nullptr, vb1, NB, nullptr, 0, nullptr, 0);
  gemm_bt<0><<<dim3(16, 2, 16), 256, 0, stream>>>(vb1, NB, 1024, St, SB, 1024, 1024,
      cini + 1 * NB, CI, nullptr, vb0, NB, nullptr, 0, nullptr, 0);
  gemm_bt<2><<<dim3(16, 2, 16), 256, 0, stream>>>(vb0, NB, 1024, St, SB, 1024, 1024,
      cini, CI, nullptr, nullptr, 0, out, NB, nullptr, 0);
}